// Round 16
// baseline (82.950 us; speedup 1.0000x reference)
//
#include <hip/hip_runtime.h>
#include <hip/hip_bf16.h>
#include <cstdint>

using f32x4 = __attribute__((ext_vector_type(4))) float;
typedef unsigned short u16;
typedef unsigned char u8;

#define B_DIM 64
#define N_DIM 1024
#define P_DIM 256
#define NTILE 8            // N / 128
#define NUPPER 36          // NTILE*(NTILE+1)/2
#define NB_PREP 16384      // (B*N)/4
#define NB_GRAM 2304       // B * NUPPER (divisible by 8 — bijective XCD swizzle)

// ---------------------------------------------------------------------------
// Kernel 1: fused BCE partial + per-row sumsq + fp32->fp8(e4m3) cast.
// ---------------------------------------------------------------------------
__global__ __launch_bounds__(256) void prep_kernel(
    const float* __restrict__ X, const float* __restrict__ T,
    u8* __restrict__ Xf8, float* __restrict__ sq,
    float* __restrict__ pb) {
  int tid  = threadIdx.x;
  int w    = tid >> 6, lane = tid & 63;
  size_t row = (size_t)blockIdx.x * 4 + w;
  const float4 xv = ((const float4*)(X + row * P_DIM))[lane];
  const float4 tv = ((const float4*)(T + row * P_DIM))[lane];
  float xs[4] = {xv.x, xv.y, xv.z, xv.w};
  float ts[4] = {tv.x, tv.y, tv.z, tv.w};
  float sqp = 0.f, bce = 0.f;
  #pragma unroll
  for (int i = 0; i < 4; ++i) {
    float x = xs[i];
    sqp += x * x;
    bce += fmaxf(x, 0.f) - x * ts[i] + __logf(1.f + __expf(-fabsf(x)));
  }
  unsigned int pk = 0;
  pk = __builtin_amdgcn_cvt_pk_fp8_f32(xs[0], xs[1], pk, false);
  pk = __builtin_amdgcn_cvt_pk_fp8_f32(xs[2], xs[3], pk, true);
  ((unsigned int*)(Xf8 + row * P_DIM))[lane] = pk;
  #pragma unroll
  for (int off = 32; off; off >>= 1) {
    sqp += __shfl_down(sqp, off);
    bce += __shfl_down(bce, off);
  }
  __shared__ float red[4];
  if (lane == 0) { sq[row] = sqp; red[w] = bce; }
  __syncthreads();
  if (tid == 0)
    pb[blockIdx.x] = red[0] + red[1] + red[2] + red[3];
}

// ---------------------------------------------------------------------------
// Kernel 2 (R16): counted-vmcnt pipeline (T3/T4) on the fp8 Gram.
// Diagnosis chain R5-R15: duration invariant to bytes/conflicts/occupancy;
// every prior structure drains vmcnt->0 per step (explicit or via
// __syncthreads' implicit waitcnt). Fix per m218/m233: global_load_lds
// staging + RAW s_barrier (no drain) + literal s_waitcnt vmcnt(4) — next
// tile's 4 loads stay in flight ACROSS barriers; drain to 0 only at the
// last tile. 4 K-tiles of BK=64 (fp8: 8KB/tile/matrix), double-buffered
// (32KB -> 4 blocks/CU). Diag blocks stage B as a duplicate of A so the
// vmcnt bookkeeping is block-uniform (literal immediates).
// Swizzle (m201 both-sides pattern, rule #21): LINEAR gload_lds dest +
// pre-swizzled SOURCE (chunk c^(r&3), permutes within one 64B line) +
// matching XOR on ds_read -> 4-way reads (1.58x, acceptable).
// sq loads moved behind sched_barrier(0) after the loop (clean vmcnt count).
// ---------------------------------------------------------------------------
__global__ __launch_bounds__(256) void gram_kernel(
    const u8* __restrict__ Xf8, const float* __restrict__ sq,
    float* __restrict__ pd) {
  __shared__ __align__(16) u8 As[2][128 * 64];   // 8 KB per buf
  __shared__ __align__(16) u8 Bs[2][128 * 64];
  __shared__ float red[4];

  // XCD-aware swizzle (nwg % 8 == 0): XCD x gets batches [8x, 8x+8).
  int p   = blockIdx.x;
  int blk = (p & 7) * (NB_GRAM / 8) + (p >> 3);
  int b   = blk / NUPPER;
  int t   = blk - b * NUPPER;
  int TI  = 0;
  while (t >= NTILE - TI) { t -= NTILE - TI; ++TI; }
  int TJ = TI + t;                                // TJ >= TI
  const bool diag = (TI == TJ);

  const u8*    Xb  = Xf8 + (size_t)b * N_DIM * P_DIM;
  const float* sqb = sq + b * N_DIM;

  const int tid  = threadIdx.x;
  const int lane = tid & 63;
  const int w    = tid >> 6;
  const int wr   = w >> 1, wc = w & 1;            // 2x2 wave grid, 64x64 each
  const bool live = !(diag && wr > wc);

  const int rowA = TI * 128, rowB = TJ * 128;

  // ---- staging geometry: per matrix per tile = 128 rows x 64B = 512 x 16B
  // chunks; thread covers chunk tid (rows 0-63) and 256+tid (rows 64-127).
  // LDS dest LINEAR (chunk idx*16 = row-major [128][64B]); source chunk
  // pre-swizzled within the row's 64B line: c_src = c_lds ^ (r&3).
  const int r0    = tid >> 2;                     // 0..63
  const int c_lds = tid & 3;
  const int c_src = c_lds ^ (r0 & 3);             // (r0+64)&3 == r0&3
  const u8* gA0 = Xb + (size_t)(rowA + r0)      * P_DIM + c_src * 16;
  const u8* gA1 = Xb + (size_t)(rowA + r0 + 64) * P_DIM + c_src * 16;
  const u8* gB0 = Xb + (size_t)(rowB + r0)      * P_DIM + c_src * 16;
  const u8* gB1 = Xb + (size_t)(rowB + r0 + 64) * P_DIM + c_src * 16;

#define GLDS(src, dst)                                                     \
  __builtin_amdgcn_global_load_lds(                                        \
      (const __attribute__((address_space(1))) void*)(src),                \
      (__attribute__((address_space(3))) void*)(dst), 16, 0, 0)

  // 4 gload_lds per STAGE per thread (uniform, incl. diag: B = copy of A).
#define STAGE(buf, k0) do {                                                \
    GLDS(gA0 + (k0), &As[buf][(size_t)tid * 16]);                          \
    GLDS(gA1 + (k0), &As[buf][4096 + (size_t)tid * 16]);                   \
    GLDS(gB0 + (k0), &Bs[buf][(size_t)tid * 16]);                         \
    GLDS(gB1 + (k0), &Bs[buf][4096 + (size_t)tid * 16]);                  \
  } while (0)

#define VMWAIT(N) do {                                                     \
    asm volatile("s_waitcnt vmcnt(" #N ")" ::: "memory");                  \
    __builtin_amdgcn_sched_barrier(0);                                     \
  } while (0)

  // ---- read geometry: frag row = base + m*16 + h (h = lane&15); k-slot
  // ks = lane>>4; logical chunk c = kk*2 + (ks>>1); swizzled byte offset
  // within row = ((c ^ (h&3)) << 4) + ((ks&1) << 3).  row&3 == h&3.
  const int h = lane & 15, ks = lane >> 4;
  const int off0 = ((((ks >> 1))     ^ (h & 3)) << 4) + ((ks & 1) << 3);
  const int off1 = (((2 + (ks >> 1)) ^ (h & 3)) << 4) + ((ks & 1) << 3);
  const int arow = (wr * 64 + h) * 64;            // + m*1024
  const int brow = (wc * 64 + h) * 64;            // + n*1024

  f32x4 acc[4][4];
  #pragma unroll
  for (int m = 0; m < 4; ++m)
    #pragma unroll
    for (int n = 0; n < 4; ++n)
      acc[m][n] = (f32x4)(0.f);

#define COMPUTE(cur) do {                                                  \
    if (live) {                                                            \
      const u8* Ab = As[cur];                                              \
      const u8* Bb = Bs[cur];                                              \
      _Pragma("unroll")                                                    \
      for (int kk = 0; kk < 2; ++kk) {                                     \
        const int off = kk ? off1 : off0;                                  \
        long long af[4], bf[4];                                            \
        _Pragma("unroll")                                                  \
        for (int m = 0; m < 4; ++m)                                        \
          af[m] = *(const long long*)&Ab[arow + m * 1024 + off];           \
        _Pragma("unroll")                                                  \
        for (int n = 0; n < 4; ++n)                                        \
          bf[n] = *(const long long*)&Bb[brow + n * 1024 + off];           \
        __builtin_amdgcn_s_setprio(1);                                     \
        _Pragma("unroll")                                                  \
        for (int m = 0; m < 4; ++m)                                        \
          _Pragma("unroll")                                                \
          for (int n = 0; n < 4; ++n)                                      \
            acc[m][n] = __builtin_amdgcn_mfma_f32_16x16x32_fp8_fp8(        \
                af[m], bf[n], acc[m][n], 0, 0, 0);                         \
        __builtin_amdgcn_s_setprio(0);                                     \
      }                                                                    \
    }                                                                      \
  } while (0)

  // ---- prologue: tiles 0 and 1 in flight (8 outstanding VMEM per wave).
  STAGE(0, 0);
  STAGE(1, 64);

  // ---- tile 0: wait t0's 4 (leave t1's 4 in flight), compute, stage t2.
  VMWAIT(4);
  __builtin_amdgcn_s_barrier();
  COMPUTE(0);
  __builtin_amdgcn_s_barrier();     // all waves done reading buf0
  STAGE(0, 128);                    // t2 -> buf0; outstanding = 8

  // ---- tile 1
  VMWAIT(4);
  __builtin_amdgcn_s_barrier();
  COMPUTE(1);
  __builtin_amdgcn_s_barrier();
  STAGE(1, 192);                    // t3 -> buf1; outstanding = 8

  // ---- tile 2
  VMWAIT(4);
  __builtin_amdgcn_s_barrier();
  COMPUTE(0);
  __builtin_amdgcn_s_barrier();     // outstanding = 4 (t3)

  // ---- tile 3 (final: drain)
  VMWAIT(0);
  __builtin_amdgcn_s_barrier();
  COMPUTE(1);

  __builtin_amdgcn_sched_barrier(0);  // fence: keep epilogue VMEM out of loop

#undef COMPUTE
#undef STAGE
#undef GLDS
#undef VMWAIT

  // Epilogue: C layout (m89/m91, dtype-independent): col = lane&15,
  // row = (lane>>4)*4 + v.
  float s = 0.f;
  if (live) {
    int rb2 = rowA + wr * 64, cb = rowB + wc * 64;
    float sqa[16], sqc[4];
    #pragma unroll
    for (int m = 0; m < 4; ++m)
      #pragma unroll
      for (int v = 0; v < 4; ++v)
        sqa[m * 4 + v] = sqb[rb2 + m * 16 + ks * 4 + v];
    #pragma unroll
    for (int n = 0; n < 4; ++n)
      sqc[n] = sqb[cb + n * 16 + h];
    #pragma unroll
    for (int m = 0; m < 4; ++m) {
      #pragma unroll
      for (int n = 0; n < 4; ++n) {
        #pragma unroll
        for (int v = 0; v < 4; ++v) {
          int gi = rb2 + m * 16 + ks * 4 + v;
          int gj = cb + n * 16 + h;
          if (gi < gj) {
            float d2 = sqa[m * 4 + v] + sqc[n] - 2.f * acc[m][n][v];
            s += sqrtf(fmaxf(d2, 0.f));
          }
        }
      }
    }
  }
  #pragma unroll
  for (int off = 32; off; off >>= 1) s += __shfl_down(s, off);
  __syncthreads();                  // full drain OK here (loop done)
  if (lane == 0) red[w] = s;
  __syncthreads();
  if (tid == 0)
    pd[blockIdx.x] = red[0] + red[1] + red[2] + red[3];
}

// ---------------------------------------------------------------------------
// Kernel 3: reduce partials (double) and combine.
// ---------------------------------------------------------------------------
__global__ __launch_bounds__(256) void finalize_kernel(
    const float* __restrict__ pb, const float* __restrict__ pd,
    float* __restrict__ out) {
  int tid = threadIdx.x;
  double s = 0.0, d = 0.0;
  for (int i = tid; i < NB_PREP; i += 256) s += (double)pb[i];
  for (int i = tid; i < NB_GRAM; i += 256) d += (double)pd[i];
  #pragma unroll
  for (int off = 32; off; off >>= 1) {
    s += __shfl_down(s, off);
    d += __shfl_down(d, off);
  }
  __shared__ double sb[4], db[4];
  int w = tid >> 6, lane = tid & 63;
  if (lane == 0) { sb[w] = s; db[w] = d; }
  __syncthreads();
  if (tid == 0) {
    double bce = (sb[0] + sb[1] + sb[2] + sb[3]) /
                 (double)((size_t)B_DIM * N_DIM * P_DIM);
    double reg = (db[0] + db[1] + db[2] + db[3]) / (double)N_DIM;
    out[0] = (float)(bce - reg);
  }
}

extern "C" void kernel_launch(void* const* d_in, const int* in_sizes, int n_in,
                              void* d_out, int out_size, void* d_ws, size_t ws_size,
                              hipStream_t stream) {
  const float* X = (const float*)d_in[0];
  const float* T = (const float*)d_in[1];
  float* out = (float*)d_out;

  // ws layout:
  //   [0, 64KB)        pb  — per-block BCE partials (16384 f32)
  //   [64KB, 74KB)     pd  — per-block dist partials (2304 f32)
  //   [80KB, 336KB)    sq  — per-row sum of squares (65536 f32)
  //   [336KB, ~17MB)   Xf8 — fp8 e4m3 copy of X (16.8 MB)
  float* pb  = (float*)d_ws;
  float* pd  = (float*)((char*)d_ws + (64 << 10));
  float* sq  = (float*)((char*)d_ws + (80 << 10));
  u8*    Xf8 = (u8*)  ((char*)d_ws + (336 << 10));

  prep_kernel<<<NB_PREP, 256, 0, stream>>>(X, T, Xf8, sq, pb);
  gram_kernel<<<NB_GRAM, 256, 0, stream>>>(Xf8, sq, pd);
  finalize_kernel<<<1, 256, 0, stream>>>(pb, pd, out);
}